// Round 2
// baseline (472.610 us; speedup 1.0000x reference)
//
#include <hip/hip_runtime.h>

#define NTOK 32768      // 8*4096 tokens
#define HDIM 1024
#define NEXP 64
#define TK   8
#define NB   8
#define SEQ  4096

#define TB   64         // tokens per block (= lanes per wave)
#define KQ   256        // K-slice per wave (4 waves cover K=1024)
#define PP   68         // partials pitch (floats); row base 272 B, 16-aligned
#define NTHR 256

// lane = token; wave = K-quarter. W loads are wave-uniform -> s_load (SGPR
// broadcast), A loads are per-lane dense 64B lines. No LDS, no barriers in
// the main loop. fp32 slice-dot accumulation, fp64 cross-wave combine.
__global__ __launch_bounds__(NTHR, 2) void moe_main(
    const float* __restrict__ hidden,   // [NTOK][HDIM]
    const float* __restrict__ weight,   // [NEXP][HDIM]
    float* __restrict__ out,            // idx[NTOK*TK] | w[NTOK*TK] | aux | counts[64]
    float* __restrict__ ws)             // C[8][64] | Sm[8][64]
{
    __shared__ __align__(16) float sPart[4 * TB * PP];   // 69632 B
    __shared__ float smSum[NEXP];
    __shared__ int   hist[NEXP];

    const int tid  = threadIdx.x;
    const int w    = tid >> 6;          // wave id = K quarter
    const int lane = tid & 63;          // token within block
    const int t0   = blockIdx.x * TB;

    if (tid < NEXP) { smSum[tid] = 0.f; hist[tid] = 0; }

    float acc[NEXP];
#pragma unroll
    for (int e = 0; e < NEXP; ++e) acc[e] = 0.f;

    const float* __restrict__ arow = hidden + (size_t)(t0 + lane) * HDIM + w * KQ;
    const int kbase = w * KQ;

    for (int s = 0; s < KQ / 16; ++s) {          // 16 slices of k16
        const float* ap = arow + s * 16;
        float4 a0 = *(const float4*)(ap + 0);
        float4 a1 = *(const float4*)(ap + 4);
        float4 a2 = *(const float4*)(ap + 8);
        float4 a3 = *(const float4*)(ap + 12);
        const float* __restrict__ wp = weight + kbase + s * 16;
#pragma unroll
        for (int e = 0; e < NEXP; ++e) {
            const float* we = wp + (size_t)e * HDIM;   // wave-uniform address
            float4 w0 = *(const float4*)(we + 0);
            float4 w1 = *(const float4*)(we + 4);
            float4 w2 = *(const float4*)(we + 8);
            float4 w3 = *(const float4*)(we + 12);
            float tmp;
            tmp = a0.x * w0.x;
            tmp = fmaf(a0.y, w0.y, tmp);
            tmp = fmaf(a0.z, w0.z, tmp);
            tmp = fmaf(a0.w, w0.w, tmp);
            tmp = fmaf(a1.x, w1.x, tmp);
            tmp = fmaf(a1.y, w1.y, tmp);
            tmp = fmaf(a1.z, w1.z, tmp);
            tmp = fmaf(a1.w, w1.w, tmp);
            tmp = fmaf(a2.x, w2.x, tmp);
            tmp = fmaf(a2.y, w2.y, tmp);
            tmp = fmaf(a2.z, w2.z, tmp);
            tmp = fmaf(a2.w, w2.w, tmp);
            tmp = fmaf(a3.x, w3.x, tmp);
            tmp = fmaf(a3.y, w3.y, tmp);
            tmp = fmaf(a3.z, w3.z, tmp);
            tmp = fmaf(a3.w, w3.w, tmp);
            acc[e] += tmp;
        }
    }

    // partials -> LDS: [quarter][token][expert], pitch PP
#pragma unroll
    for (int e = 0; e < NEXP; e += 4) {
        float4 v = make_float4(acc[e], acc[e + 1], acc[e + 2], acc[e + 3]);
        *(float4*)(&sPart[(w * TB + lane) * PP + e]) = v;
    }
    __syncthreads();

    // ---- phase 2: per-token softmax + top-8; wave w handles tokens [16w,16w+16) ----
    float regSm = 0.f;
    for (int j = 0; j < 16; ++j) {
        int tt = w * 16 + j;
        const float* pr = &sPart[tt * PP + lane];   // lane = expert now
        double xd = ((double)pr[0 * TB * PP] + (double)pr[1 * TB * PP])
                  + ((double)pr[2 * TB * PP] + (double)pr[3 * TB * PP]);
        float x = (float)xd;
        float mx = x;
#pragma unroll
        for (int off = 32; off; off >>= 1) mx = fmaxf(mx, __shfl_xor(mx, off));
        float p = __expf(x - mx);
        float sden = p;
#pragma unroll
        for (int off = 32; off; off >>= 1) sden += __shfl_xor(sden, off);
        float score = p / sden;
        regSm += score;

        // top-8 on fp64 logits (monotone w/ softmax); tie -> smaller index.
        double vd = xd;
        int selIdx = 0; float selVal = 0.f;
#pragma unroll
        for (int r = 0; r < TK; ++r) {
            unsigned long long u = (unsigned long long)__double_as_longlong(vd);
            unsigned long long mk = (u & 0x8000000000000000ull) ? ~u : (u | 0x8000000000000000ull);
            unsigned long long key = (mk & 0xFFFFFFFFFFFFFFC0ull) | (unsigned long long)(63 - lane);
#pragma unroll
            for (int off = 32; off; off >>= 1) {
                unsigned long long o = __shfl_xor(key, off);
                if (o > key) key = o;
            }
            int winner = 63 - (int)(key & 63ull);
            float wsc = __shfl(score, winner);
            if (lane == r) { selIdx = winner; selVal = wsc; }
            if (lane == winner) vd = -__builtin_inf();
        }
        float dv = (lane < TK) ? selVal : 0.f;
#pragma unroll
        for (int off = 32; off; off >>= 1) dv += __shfl_xor(dv, off);
        int t = t0 + tt;
        if (lane < TK) {
            out[(size_t)t * TK + lane] = (float)selIdx;                       // indices (as float)
            out[(size_t)NTOK * TK + (size_t)t * TK + lane] = selVal / (dv + 1e-20f);
            atomicAdd(&hist[selIdx], 1);
        }
    }
    atomicAdd(&smSum[lane], regSm);
    __syncthreads();
    if (tid < NEXP) {
        int b = blockIdx.x >> 6;            // 64 blocks per batch element
        atomicAdd(&ws[b * NEXP + tid], (float)hist[tid]);
        atomicAdd(&ws[NB * NEXP + b * NEXP + tid], smSum[tid]);
    }
}

__global__ void moe_finalize(const float* __restrict__ ws, float* __restrict__ out)
{
    int e = threadIdx.x;   // 64 threads
    float cnt = 0.f, accv = 0.f;
#pragma unroll
    for (int b = 0; b < NB; ++b) {
        float c  = ws[b * NEXP + e];
        float sm = ws[NB * NEXP + b * NEXP + e];
        cnt += c;
        accv += c * sm;
    }
    out[(size_t)NTOK * TK * 2 + 1 + e] = cnt;   // expert_counts (as float)
#pragma unroll
    for (int off = 32; off; off >>= 1) accv += __shfl_xor(accv, off);
    if (e == 0) {
        // aux = ALPHA * (1/NB) * sum_{b,e} C[b][e]*(NEXP/(SEQ*TK)) * (Sm[b][e]/SEQ)
        float aux = 0.01f * accv * ((float)NEXP / ((float)SEQ * (float)TK))
                    / (float)SEQ / (float)NB;
        out[(size_t)NTOK * TK * 2] = aux;
    }
}

extern "C" void kernel_launch(void* const* d_in, const int* in_sizes, int n_in,
                              void* d_out, int out_size, void* d_ws, size_t ws_size,
                              hipStream_t stream)
{
    const float* hidden = (const float*)d_in[0];
    const float* weight = (const float*)d_in[1];
    float* out = (float*)d_out;
    float* ws  = (float*)d_ws;

    hipMemsetAsync(d_ws, 0, 2 * NB * NEXP * sizeof(float), stream);
    moe_main<<<NTOK / TB, NTHR, 0, stream>>>(hidden, weight, out, ws);
    moe_finalize<<<1, 64, 0, stream>>>(ws, out);
}

// Round 3
// 458.061 us; speedup vs baseline: 1.0318x; 1.0318x over previous
//
#include <hip/hip_runtime.h>

#define NTOK 32768      // 8*4096 tokens
#define HDIM 1024
#define NEXP 64
#define TK   8
#define NB   8
#define SEQ  4096

#define TB   64         // tokens per block (= lanes per wave)
#define KQ   256        // K-slice per wave (4 waves cover K=1024)
#define NSL  (KQ / 16)  // 16 k16-slices per wave
#define PP   68         // partials pitch (floats)
#define NTHR 256

// lane = token; wave = K-quarter. W addresses are uniform BY CONSTRUCTION
// (readfirstlane on the K offset) -> s_load into SGPRs -> v_fma_f32 with
// SGPR W operand. A: per-lane 64B-line reads, register double-buffered.
// No LDS, no barriers, no vector W loads in the main loop.
__global__ __launch_bounds__(NTHR, 2) void moe_main(
    const float* __restrict__ hidden,   // [NTOK][HDIM]
    const float* __restrict__ weight,   // [NEXP][HDIM]
    float* __restrict__ out,            // idx[NTOK*TK] | w[NTOK*TK] | aux | counts[64]
    float* __restrict__ ws)             // C[8][64] | Sm[8][64]
{
    __shared__ __align__(16) float sPart[4 * TB * PP];   // 69632 B
    __shared__ float smSum[NEXP];
    __shared__ int   hist[NEXP];

    const int tid  = threadIdx.x;
    const int w    = tid >> 6;          // wave id = K quarter
    const int lane = tid & 63;          // token within block
    const int t0   = blockIdx.x * TB;

    if (tid < NEXP) { smSum[tid] = 0.f; hist[tid] = 0; }

    float acc[NEXP];
#pragma unroll
    for (int e = 0; e < NEXP; ++e) acc[e] = 0.f;

    // Uniform-by-construction K offset -> scalar (SMEM) W loads.
    const int kb = __builtin_amdgcn_readfirstlane(w * KQ);
    const float* __restrict__ wq   = weight + kb;
    const float* __restrict__ arow = hidden + (size_t)(t0 + lane) * HDIM + kb;

    float4 a0 = *(const float4*)(arow + 0);
    float4 a1 = *(const float4*)(arow + 4);
    float4 a2 = *(const float4*)(arow + 8);
    float4 a3 = *(const float4*)(arow + 12);

    for (int s = 0; s < NSL; ++s) {
        // prefetch next A slice (guarded: last iter re-reads slice 0, discarded)
        const float* pf = arow + ((s + 1 < NSL) ? (s + 1) * 16 : 0);
        float4 n0 = *(const float4*)(pf + 0);
        float4 n1 = *(const float4*)(pf + 4);
        float4 n2 = *(const float4*)(pf + 8);
        float4 n3 = *(const float4*)(pf + 12);

        const float* wp = wq + s * 16;
#pragma unroll
        for (int e = 0; e < NEXP; ++e) {
            const float4* wf = (const float4*)(wp + (size_t)e * HDIM);  // uniform
            float4 w0 = wf[0], w1 = wf[1], w2 = wf[2], w3 = wf[3];
            float tmp;
            tmp = a0.x * w0.x;
            tmp = fmaf(a0.y, w0.y, tmp);
            tmp = fmaf(a0.z, w0.z, tmp);
            tmp = fmaf(a0.w, w0.w, tmp);
            tmp = fmaf(a1.x, w1.x, tmp);
            tmp = fmaf(a1.y, w1.y, tmp);
            tmp = fmaf(a1.z, w1.z, tmp);
            tmp = fmaf(a1.w, w1.w, tmp);
            tmp = fmaf(a2.x, w2.x, tmp);
            tmp = fmaf(a2.y, w2.y, tmp);
            tmp = fmaf(a2.z, w2.z, tmp);
            tmp = fmaf(a2.w, w2.w, tmp);
            tmp = fmaf(a3.x, w3.x, tmp);
            tmp = fmaf(a3.y, w3.y, tmp);
            tmp = fmaf(a3.z, w3.z, tmp);
            tmp = fmaf(a3.w, w3.w, tmp);
            acc[e] += tmp;
        }
        a0 = n0; a1 = n1; a2 = n2; a3 = n3;
    }

    // partials -> LDS: [quarter][token][expert], pitch PP
#pragma unroll
    for (int e = 0; e < NEXP; e += 4) {
        float4 v = make_float4(acc[e], acc[e + 1], acc[e + 2], acc[e + 3]);
        *(float4*)(&sPart[(w * TB + lane) * PP + e]) = v;
    }
    __syncthreads();

    // ---- phase 2: per-token softmax + top-8; wave w handles tokens [16w,16w+16) ----
    float regSm = 0.f;
    for (int j = 0; j < 16; ++j) {
        int tt = w * 16 + j;
        const float* pr = &sPart[tt * PP + lane];   // lane = expert now
        double xd = ((double)pr[0 * TB * PP] + (double)pr[1 * TB * PP])
                  + ((double)pr[2 * TB * PP] + (double)pr[3 * TB * PP]);
        float x = (float)xd;
        float mx = x;
#pragma unroll
        for (int off = 32; off; off >>= 1) mx = fmaxf(mx, __shfl_xor(mx, off));
        float p = __expf(x - mx);
        float sden = p;
#pragma unroll
        for (int off = 32; off; off >>= 1) sden += __shfl_xor(sden, off);
        float score = p / sden;
        regSm += score;

        // top-8 on fp64 logits (monotone w/ softmax); tie -> smaller index.
        double vd = xd;
        int selIdx = 0; float selVal = 0.f;
#pragma unroll
        for (int r = 0; r < TK; ++r) {
            unsigned long long u = (unsigned long long)__double_as_longlong(vd);
            unsigned long long mk = (u & 0x8000000000000000ull) ? ~u : (u | 0x8000000000000000ull);
            unsigned long long key = (mk & 0xFFFFFFFFFFFFFFC0ull) | (unsigned long long)(63 - lane);
#pragma unroll
            for (int off = 32; off; off >>= 1) {
                unsigned long long o = __shfl_xor(key, off);
                if (o > key) key = o;
            }
            int winner = 63 - (int)(key & 63ull);
            float wsc = __shfl(score, winner);
            if (lane == r) { selIdx = winner; selVal = wsc; }
            if (lane == winner) vd = -__builtin_inf();
        }
        float dv = (lane < TK) ? selVal : 0.f;
#pragma unroll
        for (int off = 32; off; off >>= 1) dv += __shfl_xor(dv, off);
        int t = t0 + tt;
        if (lane < TK) {
            out[(size_t)t * TK + lane] = (float)selIdx;                       // indices (as float)
            out[(size_t)NTOK * TK + (size_t)t * TK + lane] = selVal / (dv + 1e-20f);
            atomicAdd(&hist[selIdx], 1);
        }
    }
    atomicAdd(&smSum[lane], regSm);
    __syncthreads();
    if (tid < NEXP) {
        int b = blockIdx.x >> 6;            // 64 blocks per batch element
        atomicAdd(&ws[b * NEXP + tid], (float)hist[tid]);
        atomicAdd(&ws[NB * NEXP + b * NEXP + tid], smSum[tid]);
    }
}

__global__ void moe_finalize(const float* __restrict__ ws, float* __restrict__ out)
{
    int e = threadIdx.x;   // 64 threads
    float cnt = 0.f, accv = 0.f;
#pragma unroll
    for (int b = 0; b < NB; ++b) {
        float c  = ws[b * NEXP + e];
        float sm = ws[NB * NEXP + b * NEXP + e];
        cnt += c;
        accv += c * sm;
    }
    out[(size_t)NTOK * TK * 2 + 1 + e] = cnt;   // expert_counts (as float)
#pragma unroll
    for (int off = 32; off; off >>= 1) accv += __shfl_xor(accv, off);
    if (e == 0) {
        // aux = ALPHA * (1/NB) * sum_{b,e} C[b][e]*(NEXP/(SEQ*TK)) * (Sm[b][e]/SEQ)
        float aux = 0.01f * accv * ((float)NEXP / ((float)SEQ * (float)TK))
                    / (float)SEQ / (float)NB;
        out[(size_t)NTOK * TK * 2] = aux;
    }
}

extern "C" void kernel_launch(void* const* d_in, const int* in_sizes, int n_in,
                              void* d_out, int out_size, void* d_ws, size_t ws_size,
                              hipStream_t stream)
{
    const float* hidden = (const float*)d_in[0];
    const float* weight = (const float*)d_in[1];
    float* out = (float*)d_out;
    float* ws  = (float*)d_ws;

    hipMemsetAsync(d_ws, 0, 2 * NB * NEXP * sizeof(float), stream);
    moe_main<<<NTOK / TB, NTHR, 0, stream>>>(hidden, weight, out, ws);
    moe_finalize<<<1, 64, 0, stream>>>(ws, out);
}

// Round 4
// 300.441 us; speedup vs baseline: 1.5731x; 1.5246x over previous
//
#include <hip/hip_runtime.h>

#define NTOK 32768      // 8*4096 tokens
#define HDIM 1024
#define NEXP 64
#define TK   8
#define NB   8
#define SEQ  4096

#define MB   64         // tokens per block
#define KC   64         // K chunk
#define PIT  72         // LDS row pitch (bf16): 64 + 8 pad -> 2-way max (free)
#define NTHR 128        // 2 waves

typedef __attribute__((ext_vector_type(8))) short bf16x8;   // 8 bf16 = 4 VGPRs
typedef __attribute__((ext_vector_type(4))) float f32x4;

__device__ inline unsigned f2bf(float x) {          // RTN-even fp32 -> bf16 bits
    unsigned u = __float_as_uint(x);
    return (u + 0x7FFFu + ((u >> 16) & 1u)) >> 16;
}

// bf16x3 split GEMM: logits = A*W^T with A,W split hi/lo bf16; 3 MFMA passes
// (hi*hi + lo*hi + hi*lo) -> fp32 acc, error ~2^-16 rel (verified headroom:
// exact-vs-ref absmax 57 < 91.5 threshold; perturbation ~1e-5 adds few flips).
__global__ __launch_bounds__(NTHR) void moe_main(
    const float* __restrict__ hidden,   // [NTOK][HDIM]
    const float* __restrict__ weight,   // [NEXP][HDIM]
    float* __restrict__ out,            // idx[NTOK*TK] | w[NTOK*TK] | aux | counts[64]
    float* __restrict__ ws)             // C[8][64] | Sm[8][64]
{
    __shared__ __align__(16) unsigned short sm[4 * MB * PIT];  // 36864 B
    unsigned short* Ah = sm;                  // [64][PIT]
    unsigned short* Al = sm + MB * PIT;
    unsigned short* Bh = sm + 2 * MB * PIT;
    unsigned short* Bl = sm + 3 * MB * PIT;
    float* sLog = (float*)sm;                 // [64][65] alias (post-GEMM)
    __shared__ float smSum[NEXP];
    __shared__ int   hist[NEXP];

    const int tid = threadIdx.x;
    const int w   = tid >> 6;           // wave 0/1
    const int l   = tid & 63;
    const int t0  = blockIdx.x * MB;

    if (tid < NEXP) { smSum[tid] = 0.f; hist[tid] = 0; }

    // prefetch chunk 0: 8 float4 of A rows + 8 of W rows per thread
    float4 ra[8], rb[8];
#pragma unroll
    for (int i = 0; i < 8; ++i) {
        int idx = i * NTHR + tid;
        int row = idx >> 4, kq = idx & 15;
        ra[i] = *(const float4*)(hidden + (size_t)(t0 + row) * HDIM + kq * 4);
        rb[i] = *(const float4*)(weight + (size_t)row * HDIM + kq * 4);
    }

    f32x4 acc[2][4];
#pragma unroll
    for (int mi = 0; mi < 2; ++mi)
#pragma unroll
        for (int ni = 0; ni < 4; ++ni) acc[mi][ni] = (f32x4)0.f;

    for (int c = 0; c < HDIM / KC; ++c) {
        // convert (Dekker split) + stage to LDS
#pragma unroll
        for (int i = 0; i < 8; ++i) {
            int idx = i * NTHR + tid;
            int row = idx >> 4, kq = idx & 15;
            float4 v = ra[i];
            unsigned h0 = f2bf(v.x), h1 = f2bf(v.y), h2 = f2bf(v.z), h3 = f2bf(v.w);
            unsigned o0 = f2bf(v.x - __uint_as_float(h0 << 16));
            unsigned o1 = f2bf(v.y - __uint_as_float(h1 << 16));
            unsigned o2 = f2bf(v.z - __uint_as_float(h2 << 16));
            unsigned o3 = f2bf(v.w - __uint_as_float(h3 << 16));
            uint2 hp = make_uint2(h0 | (h1 << 16), h2 | (h3 << 16));
            uint2 lp = make_uint2(o0 | (o1 << 16), o2 | (o3 << 16));
            *(uint2*)&Ah[row * PIT + kq * 4] = hp;
            *(uint2*)&Al[row * PIT + kq * 4] = lp;

            float4 u = rb[i];
            unsigned g0 = f2bf(u.x), g1 = f2bf(u.y), g2 = f2bf(u.z), g3 = f2bf(u.w);
            unsigned p0 = f2bf(u.x - __uint_as_float(g0 << 16));
            unsigned p1 = f2bf(u.y - __uint_as_float(g1 << 16));
            unsigned p2 = f2bf(u.z - __uint_as_float(g2 << 16));
            unsigned p3 = f2bf(u.w - __uint_as_float(g3 << 16));
            uint2 gp = make_uint2(g0 | (g1 << 16), g2 | (g3 << 16));
            uint2 qp = make_uint2(p0 | (p1 << 16), p2 | (p3 << 16));
            *(uint2*)&Bh[row * PIT + kq * 4] = gp;
            *(uint2*)&Bl[row * PIT + kq * 4] = qp;
        }
        __syncthreads();

        // prefetch next chunk while MFMAs run
        if (c + 1 < HDIM / KC) {
            int kc = (c + 1) * KC;
#pragma unroll
            for (int i = 0; i < 8; ++i) {
                int idx = i * NTHR + tid;
                int row = idx >> 4, kq = idx & 15;
                ra[i] = *(const float4*)(hidden + (size_t)(t0 + row) * HDIM + kc + kq * 4);
                rb[i] = *(const float4*)(weight + (size_t)row * HDIM + kc + kq * 4);
            }
        }

        // 2 K32 steps: wave tile M=32 x N=64, 16x16x32 MFMA
#pragma unroll
        for (int s = 0; s < 2; ++s) {
            const int ko = s * 32 + (l >> 4) * 8;   // A[m][k]: m=lane&15, k=quad*8+j
            bf16x8 ah[2], av[2], bh[4], bv[4];
#pragma unroll
            for (int mi = 0; mi < 2; ++mi) {
                int base = (w * 32 + mi * 16 + (l & 15)) * PIT + ko;
                ah[mi] = *(const bf16x8*)&Ah[base];
                av[mi] = *(const bf16x8*)&Al[base];
            }
#pragma unroll
            for (int ni = 0; ni < 4; ++ni) {
                int base = (ni * 16 + (l & 15)) * PIT + ko;
                bh[ni] = *(const bf16x8*)&Bh[base];
                bv[ni] = *(const bf16x8*)&Bl[base];
            }
#pragma unroll
            for (int ni = 0; ni < 4; ++ni)
#pragma unroll
                for (int mi = 0; mi < 2; ++mi) {
                    acc[mi][ni] = __builtin_amdgcn_mfma_f32_16x16x32_bf16(ah[mi], bh[ni], acc[mi][ni], 0, 0, 0);
                    acc[mi][ni] = __builtin_amdgcn_mfma_f32_16x16x32_bf16(av[mi], bh[ni], acc[mi][ni], 0, 0, 0);
                    acc[mi][ni] = __builtin_amdgcn_mfma_f32_16x16x32_bf16(ah[mi], bv[ni], acc[mi][ni], 0, 0, 0);
                }
        }
        __syncthreads();
    }

    // epilogue: logits -> LDS [token][expert], pitch 65
    // C/D layout: col=lane&15, row=(lane>>4)*4+reg  [m89-verified]
#pragma unroll
    for (int mi = 0; mi < 2; ++mi)
#pragma unroll
        for (int ni = 0; ni < 4; ++ni)
#pragma unroll
            for (int r = 0; r < 4; ++r)
                sLog[(w * 32 + mi * 16 + (l >> 4) * 4 + r) * 65 + ni * 16 + (l & 15)] = acc[mi][ni][r];
    __syncthreads();

    // ---- phase 2: softmax + top-8; wave w handles tokens [32w, 32w+32) ----
    float regSm = 0.f;
    for (int j = 0; j < 32; ++j) {
        int tt = w * 32 + j;
        float x = sLog[tt * 65 + l];          // lane = expert
        double xd = (double)x;
        float mx = x;
#pragma unroll
        for (int off = 32; off; off >>= 1) mx = fmaxf(mx, __shfl_xor(mx, off));
        float p = __expf(x - mx);
        float sden = p;
#pragma unroll
        for (int off = 32; off; off >>= 1) sden += __shfl_xor(sden, off);
        float score = p / sden;
        regSm += score;

        double vd = xd;
        int selIdx = 0; float selVal = 0.f;
#pragma unroll
        for (int r = 0; r < TK; ++r) {
            unsigned long long u = (unsigned long long)__double_as_longlong(vd);
            unsigned long long mk = (u & 0x8000000000000000ull) ? ~u : (u | 0x8000000000000000ull);
            unsigned long long key = (mk & 0xFFFFFFFFFFFFFFC0ull) | (unsigned long long)(63 - l);
#pragma unroll
            for (int off = 32; off; off >>= 1) {
                unsigned long long o = __shfl_xor(key, off);
                if (o > key) key = o;
            }
            int winner = 63 - (int)(key & 63ull);
            float wsc = __shfl(score, winner);
            if (l == r) { selIdx = winner; selVal = wsc; }
            if (l == winner) vd = -__builtin_inf();
        }
        float dv = (l < TK) ? selVal : 0.f;
#pragma unroll
        for (int off = 32; off; off >>= 1) dv += __shfl_xor(dv, off);
        int t = t0 + tt;
        if (l < TK) {
            out[(size_t)t * TK + l] = (float)selIdx;
            out[(size_t)NTOK * TK + (size_t)t * TK + l] = selVal / (dv + 1e-20f);
            atomicAdd(&hist[selIdx], 1);
        }
    }
    atomicAdd(&smSum[l], regSm);
    __syncthreads();
    if (tid < NEXP) {
        int b = blockIdx.x >> 6;            // 64 blocks per batch element
        atomicAdd(&ws[b * NEXP + tid], (float)hist[tid]);
        atomicAdd(&ws[NB * NEXP + b * NEXP + tid], smSum[tid]);
    }
}

__global__ void moe_finalize(const float* __restrict__ ws, float* __restrict__ out)
{
    int e = threadIdx.x;   // 64 threads
    float cnt = 0.f, accv = 0.f;
#pragma unroll
    for (int b = 0; b < NB; ++b) {
        float c  = ws[b * NEXP + e];
        float sm = ws[NB * NEXP + b * NEXP + e];
        cnt += c;
        accv += c * sm;
    }
    out[(size_t)NTOK * TK * 2 + 1 + e] = cnt;   // expert_counts (as float)
#pragma unroll
    for (int off = 32; off; off >>= 1) accv += __shfl_xor(accv, off);
    if (e == 0) {
        float aux = 0.01f * accv * ((float)NEXP / ((float)SEQ * (float)TK))
                    / (float)SEQ / (float)NB;
        out[(size_t)NTOK * TK * 2] = aux;
    }
}

extern "C" void kernel_launch(void* const* d_in, const int* in_sizes, int n_in,
                              void* d_out, int out_size, void* d_ws, size_t ws_size,
                              hipStream_t stream)
{
    const float* hidden = (const float*)d_in[0];
    const float* weight = (const float*)d_in[1];
    float* out = (float*)d_out;
    float* ws  = (float*)d_ws;

    hipMemsetAsync(d_ws, 0, 2 * NB * NEXP * sizeof(float), stream);
    moe_main<<<NTOK / MB, NTHR, 0, stream>>>(hidden, weight, out, ws);
    moe_finalize<<<1, 64, 0, stream>>>(ws, out);
}

// Round 5
// 279.025 us; speedup vs baseline: 1.6938x; 1.0768x over previous
//
#include <hip/hip_runtime.h>

#define NTOK 32768      // 8*4096 tokens
#define HDIM 1024
#define NEXP 64
#define TK   8
#define NB   8
#define SEQ  4096

#define MW   16         // tokens per block (one 16-row MFMA tile)
#define NTHR 128        // 2 waves: wave w owns K-half w

typedef __attribute__((ext_vector_type(8))) short bf16x8;   // 8 bf16 = 4 VGPRs
typedef __attribute__((ext_vector_type(4))) float f32x4;

union BF8 { bf16x8 v; unsigned u[4]; };

__device__ inline unsigned f2bf(float x) {          // RTN-even fp32 -> bf16 bits
    unsigned u = __float_as_uint(x);
    return (u + 0x7FFFu + ((u >> 16) & 1u)) >> 16;
}

__device__ inline void split4(float4 v, unsigned* hp, unsigned* lp) {
    unsigned h0 = f2bf(v.x), h1 = f2bf(v.y), h2 = f2bf(v.z), h3 = f2bf(v.w);
    unsigned l0 = f2bf(v.x - __uint_as_float(h0 << 16));
    unsigned l1 = f2bf(v.y - __uint_as_float(h1 << 16));
    unsigned l2 = f2bf(v.z - __uint_as_float(h2 << 16));
    unsigned l3 = f2bf(v.w - __uint_as_float(h3 << 16));
    hp[0] = h0 | (h1 << 16); hp[1] = h2 | (h3 << 16);
    lp[0] = l0 | (l1 << 16); lp[1] = l2 | (l3 << 16);
}

// One-time weight split: W[64][1024] fp32 -> Whi/Wlo bf16 (Dekker hi/lo).
__global__ void wsplit(const float* __restrict__ w,
                       unsigned short* __restrict__ whi,
                       unsigned short* __restrict__ wlo)
{
    int idx = blockIdx.x * 256 + threadIdx.x;       // 64 blocks -> 16384 float4
    float4 v = ((const float4*)w)[idx];
    unsigned hp[2], lp[2];
    split4(v, hp, lp);
    ((uint2*)whi)[idx] = make_uint2(hp[0], hp[1]);
    ((uint2*)wlo)[idx] = make_uint2(lp[0], lp[1]);
}

// Wave-independent bf16x3 GEMM: no LDS / no barriers in the K-loop.
// Wave w: 16 tokens x 64 experts over K-half [512w, 512w+512).
// Fragments loaded directly from global in MFMA layout (row=lane&15,
// k=quad*8+j). A split hi/lo in-register; W pre-split (L2-resident).
__global__ __launch_bounds__(NTHR, 4) void moe_main(
    const float* __restrict__ hidden,           // [NTOK][HDIM]
    const unsigned short* __restrict__ whi,     // [NEXP][HDIM] bf16 hi
    const unsigned short* __restrict__ wlo,     // [NEXP][HDIM] bf16 lo
    float* __restrict__ out,                    // idx | w | aux | counts
    float* __restrict__ ws)                     // C[8][64] | Sm[8][64]
{
    __shared__ float sLog[2][MW * 65];          // per-K-half logits, 8320 B
    __shared__ float smSum[NEXP];
    __shared__ int   hist[NEXP];

    const int tid  = threadIdx.x;
    const int w    = tid >> 6;                  // K-half
    const int l    = tid & 63;
    const int m    = l & 15;                    // fragment row
    const int quad = l >> 4;                    // fragment k-subblock
    const int t0   = blockIdx.x * MW;
    const int khalf = w * 512;

    if (tid < NEXP) { smSum[tid] = 0.f; hist[tid] = 0; }

    const float* aptr = hidden + (size_t)(t0 + m) * HDIM + khalf + quad * 8;
    const unsigned short* bhp = whi + m * HDIM + khalf + quad * 8;
    const unsigned short* blp = wlo + m * HDIM + khalf + quad * 8;

    f32x4 acc[4];
#pragma unroll
    for (int ni = 0; ni < 4; ++ni) acc[ni] = (f32x4)0.f;

    float4 a0 = *(const float4*)(aptr);
    float4 a1 = *(const float4*)(aptr + 4);
    bf16x8 bh[4], bl[4];
#pragma unroll
    for (int ni = 0; ni < 4; ++ni) {
        bh[ni] = *(const bf16x8*)(bhp + ni * 16 * HDIM);
        bl[ni] = *(const bf16x8*)(blp + ni * 16 * HDIM);
    }

    for (int s = 0; s < 16; ++s) {              // 16 K32 steps cover K-half
        const int nn = ((s + 1) & 15) * 32;     // wrap prefetch (last re-reads 0)
        float4 na0 = *(const float4*)(aptr + nn);
        float4 na1 = *(const float4*)(aptr + nn + 4);
        bf16x8 nbh[4], nbl[4];
#pragma unroll
        for (int ni = 0; ni < 4; ++ni) {
            nbh[ni] = *(const bf16x8*)(bhp + ni * 16 * HDIM + nn);
            nbl[ni] = *(const bf16x8*)(blp + ni * 16 * HDIM + nn);
        }

        BF8 ah, al;
        split4(a0, &ah.u[0], &al.u[0]);
        split4(a1, &ah.u[2], &al.u[2]);

#pragma unroll
        for (int ni = 0; ni < 4; ++ni) {
            acc[ni] = __builtin_amdgcn_mfma_f32_16x16x32_bf16(ah.v, bh[ni], acc[ni], 0, 0, 0);
            acc[ni] = __builtin_amdgcn_mfma_f32_16x16x32_bf16(al.v, bh[ni], acc[ni], 0, 0, 0);
            acc[ni] = __builtin_amdgcn_mfma_f32_16x16x32_bf16(ah.v, bl[ni], acc[ni], 0, 0, 0);
        }

        a0 = na0; a1 = na1;
#pragma unroll
        for (int ni = 0; ni < 4; ++ni) { bh[ni] = nbh[ni]; bl[ni] = nbl[ni]; }
    }

    // epilogue: C/D layout row=(lane>>4)*4+reg (token), col=lane&15 (expert)
#pragma unroll
    for (int ni = 0; ni < 4; ++ni)
#pragma unroll
        for (int r = 0; r < 4; ++r)
            sLog[w][(quad * 4 + r) * 65 + ni * 16 + m] = acc[ni][r];
    __syncthreads();

    // ---- phase 2: softmax + top-8; wave w handles tokens [8w, 8w+8) ----
    float regSm = 0.f;
    for (int j = 0; j < 8; ++j) {
        int tt = w * 8 + j;
        float x = sLog[0][tt * 65 + l] + sLog[1][tt * 65 + l];   // lane = expert
        double xd = (double)x;
        float mx = x;
#pragma unroll
        for (int off = 32; off; off >>= 1) mx = fmaxf(mx, __shfl_xor(mx, off));
        float p = __expf(x - mx);
        float sden = p;
#pragma unroll
        for (int off = 32; off; off >>= 1) sden += __shfl_xor(sden, off);
        float score = p / sden;
        regSm += score;

        double vd = xd;
        int selIdx = 0; float selVal = 0.f;
#pragma unroll
        for (int r = 0; r < TK; ++r) {
            unsigned long long u = (unsigned long long)__double_as_longlong(vd);
            unsigned long long mk = (u & 0x8000000000000000ull) ? ~u : (u | 0x8000000000000000ull);
            unsigned long long key = (mk & 0xFFFFFFFFFFFFFFC0ull) | (unsigned long long)(63 - l);
#pragma unroll
            for (int off = 32; off; off >>= 1) {
                unsigned long long o = __shfl_xor(key, off);
                if (o > key) key = o;
            }
            int winner = 63 - (int)(key & 63ull);
            float wsc = __shfl(score, winner);
            if (l == r) { selIdx = winner; selVal = wsc; }
            if (l == winner) vd = -__builtin_inf();
        }
        float dv = (l < TK) ? selVal : 0.f;
#pragma unroll
        for (int off = 32; off; off >>= 1) dv += __shfl_xor(dv, off);
        int t = t0 + tt;
        if (l < TK) {
            out[(size_t)t * TK + l] = (float)selIdx;
            out[(size_t)NTOK * TK + (size_t)t * TK + l] = selVal / (dv + 1e-20f);
            atomicAdd(&hist[selIdx], 1);
        }
    }
    atomicAdd(&smSum[l], regSm);
    __syncthreads();
    if (tid < NEXP) {
        int b = blockIdx.x >> 8;            // 256 blocks per batch element
        atomicAdd(&ws[b * NEXP + tid], (float)hist[tid]);
        atomicAdd(&ws[NB * NEXP + b * NEXP + tid], smSum[tid]);
    }
}

__global__ void moe_finalize(const float* __restrict__ ws, float* __restrict__ out)
{
    int e = threadIdx.x;   // 64 threads
    float cnt = 0.f, accv = 0.f;
#pragma unroll
    for (int b = 0; b < NB; ++b) {
        float c  = ws[b * NEXP + e];
        float sm = ws[NB * NEXP + b * NEXP + e];
        cnt += c;
        accv += c * sm;
    }
    out[(size_t)NTOK * TK * 2 + 1 + e] = cnt;   // expert_counts (as float)
#pragma unroll
    for (int off = 32; off; off >>= 1) accv += __shfl_xor(accv, off);
    if (e == 0) {
        float aux = 0.01f * accv * ((float)NEXP / ((float)SEQ * (float)TK))
                    / (float)SEQ / (float)NB;
        out[(size_t)NTOK * TK * 2] = aux;
    }
}

extern "C" void kernel_launch(void* const* d_in, const int* in_sizes, int n_in,
                              void* d_out, int out_size, void* d_ws, size_t ws_size,
                              hipStream_t stream)
{
    const float* hidden = (const float*)d_in[0];
    const float* weight = (const float*)d_in[1];
    float* out  = (float*)d_out;
    float* wsf  = (float*)d_ws;
    unsigned short* whi = (unsigned short*)(wsf + 2 * NB * NEXP);   // +4096 B
    unsigned short* wlo = whi + NEXP * HDIM;

    hipMemsetAsync(d_ws, 0, 2 * NB * NEXP * sizeof(float), stream);
    wsplit<<<64, 256, 0, stream>>>(weight, whi, wlo);
    moe_main<<<NTOK / MW, NTHR, 0, stream>>>(hidden, whi, wlo, out, wsf);
    moe_finalize<<<1, 64, 0, stream>>>(wsf, out);
}

// Round 6
// 262.705 us; speedup vs baseline: 1.7990x; 1.0621x over previous
//
#include <hip/hip_runtime.h>

#define NTOK 32768      // 8*4096 tokens
#define HDIM 1024
#define NEXP 64
#define TK   8
#define NB   8
#define SEQ  4096

#define MB   64         // tokens per block
#define KC   64         // K chunk (16 chunks)
#define NTHR 256        // 4 waves; wave w owns token rows [16w,16w+16)

typedef __attribute__((ext_vector_type(8))) short bf16x8;   // 8 bf16 = 4 VGPRs
typedef __attribute__((ext_vector_type(4))) float f32x4;

union BF8 { bf16x8 v; unsigned u[4]; };

__device__ inline unsigned f2bf(float x) {          // RTN-even fp32 -> bf16 bits
    unsigned u = __float_as_uint(x);
    return (u + 0x7FFFu + ((u >> 16) & 1u)) >> 16;
}

__device__ inline void split4(float4 v, unsigned* hp, unsigned* lp) {
    unsigned h0 = f2bf(v.x), h1 = f2bf(v.y), h2 = f2bf(v.z), h3 = f2bf(v.w);
    unsigned l0 = f2bf(v.x - __uint_as_float(h0 << 16));
    unsigned l1 = f2bf(v.y - __uint_as_float(h1 << 16));
    unsigned l2 = f2bf(v.z - __uint_as_float(h2 << 16));
    unsigned l3 = f2bf(v.w - __uint_as_float(h3 << 16));
    hp[0] = h0 | (h1 << 16); hp[1] = h2 | (h3 << 16);
    lp[0] = l0 | (l1 << 16); lp[1] = l2 | (l3 << 16);
}

// async global->LDS, 16B per lane; LDS dest = wave-uniform base + lane*16
__device__ __forceinline__ void gl16(const void* g, void* l) {
    __builtin_amdgcn_global_load_lds(
        (const __attribute__((address_space(1))) void*)g,
        (__attribute__((address_space(3))) void*)l, 16, 0, 0);
}

// One-time weight split: W[64][1024] fp32 -> Whi/Wlo bf16 (Dekker hi/lo).
__global__ void wsplit(const float* __restrict__ w,
                       unsigned short* __restrict__ whi,
                       unsigned short* __restrict__ wlo)
{
    int idx = blockIdx.x * 256 + threadIdx.x;       // 64 blocks -> 16384 float4
    float4 v = ((const float4*)w)[idx];
    unsigned hp[2], lp[2];
    split4(v, hp, lp);
    ((uint2*)whi)[idx] = make_uint2(hp[0], hp[1]);
    ((uint2*)wlo)[idx] = make_uint2(lp[0], lp[1]);
}

// m97-style bf16x3 GEMM: global_load_lds staging (no VGPR round-trip),
// chunk-column LDS layout [16B-chunk][row] (linear for staging, B reads
// conflict-free), ds_read_b128 fragments, in-register Dekker split of A.
__global__ __launch_bounds__(NTHR, 2) void moe_main(
    const float* __restrict__ hidden,           // [NTOK][HDIM]
    const unsigned short* __restrict__ whi,     // [NEXP][HDIM] bf16 hi
    const unsigned short* __restrict__ wlo,     // [NEXP][HDIM] bf16 lo
    float* __restrict__ out,                    // idx | w | aux | counts
    float* __restrict__ ws)                     // C[8][64] | Sm[8][64]
{
    __shared__ __align__(16) unsigned char smem[32768];
    float*          sA  = (float*)smem;                        // [16][64] 16B-chunks, 16 KB
    unsigned short* sBh = (unsigned short*)(smem + 16384);     // [8][64] chunks, 8 KB
    unsigned short* sBl = (unsigned short*)(smem + 24576);     // 8 KB
    float*          sLog = (float*)smem;                       // [64][66] alias (post-GEMM)
    __shared__ float smSum[NEXP];
    __shared__ int   hist[NEXP];

    const int tid   = threadIdx.x;
    const int w     = tid >> 6;
    const int l     = tid & 63;
    const int m     = l & 15;
    const int quad  = l >> 4;
    const int t0    = blockIdx.x * MB;
    const int wbase = tid & 192;        // wave-uniform lane-group base

    if (tid < NEXP) { smSum[tid] = 0.f; hist[tid] = 0; }

    f32x4 acc[4];
#pragma unroll
    for (int n = 0; n < 4; ++n) acc[n] = (f32x4)0.f;

    for (int c = 0; c < HDIM / KC; ++c) {
        const int kc = c * KC;
        __syncthreads();                // previous chunk's reads complete
        // stage A: 1024 slots (chunk cc=slot>>6, row r=slot&63), 4 issues
#pragma unroll
        for (int i = 0; i < 4; ++i) {
            int sl = i * 256 + tid;
            int cc = sl >> 6, r = sl & 63;
            gl16(hidden + (size_t)(t0 + r) * HDIM + kc + cc * 4,
                 smem + (size_t)(i * 256 + wbase) * 16);
        }
        // stage Bh/Bl: 512 slots each, 2 issues each
#pragma unroll
        for (int i = 0; i < 2; ++i) {
            int sl = i * 256 + tid;
            int cc = sl >> 6, r = sl & 63;
            gl16(whi + (size_t)r * HDIM + kc + cc * 8,
                 smem + 16384 + (size_t)(i * 256 + wbase) * 16);
            gl16(wlo + (size_t)r * HDIM + kc + cc * 8,
                 smem + 24576 + (size_t)(i * 256 + wbase) * 16);
        }
        __syncthreads();                // vmcnt drained by barrier semantics

        // 2 K32 steps; wave tile M=16 x N=64
#pragma unroll
        for (int s = 0; s < 2; ++s) {
            const int c0 = 8 * s + 2 * quad;       // A chunk pair
            const int ar = w * 16 + m;             // token row
            float4 a0 = *(const float4*)&sA[c0 * 256 + ar * 4];
            float4 a1 = *(const float4*)&sA[(c0 + 1) * 256 + ar * 4];
            BF8 ah, al;
            split4(a0, &ah.u[0], &al.u[0]);
            split4(a1, &ah.u[2], &al.u[2]);
            const int cb = 4 * s + quad;           // B chunk
#pragma unroll
            for (int n = 0; n < 4; ++n) {
                const int br = n * 16 + m;         // expert row
                bf16x8 bh = *(const bf16x8*)&sBh[cb * 512 + br * 8];
                bf16x8 bl = *(const bf16x8*)&sBl[cb * 512 + br * 8];
                acc[n] = __builtin_amdgcn_mfma_f32_16x16x32_bf16(ah.v, bh, acc[n], 0, 0, 0);
                acc[n] = __builtin_amdgcn_mfma_f32_16x16x32_bf16(al.v, bh, acc[n], 0, 0, 0);
                acc[n] = __builtin_amdgcn_mfma_f32_16x16x32_bf16(ah.v, bl, acc[n], 0, 0, 0);
            }
        }
    }

    __syncthreads();                    // all LDS reads done before sLog overwrite
    // epilogue: C/D layout row=(lane>>4)*4+reg (token), col=lane&15 (expert)
#pragma unroll
    for (int n = 0; n < 4; ++n)
#pragma unroll
        for (int r = 0; r < 4; ++r)
            sLog[(w * 16 + quad * 4 + r) * 66 + n * 16 + m] = acc[n][r];
    __syncthreads();

    // ---- phase 2: softmax + top-8; wave w handles tokens [16w, 16w+16) ----
    float regSm = 0.f;
    for (int j = 0; j < 16; ++j) {
        int tt = w * 16 + j;
        float x = sLog[tt * 66 + l];               // lane = expert
        double xd = (double)x;
        float mx = x;
#pragma unroll
        for (int off = 32; off; off >>= 1) mx = fmaxf(mx, __shfl_xor(mx, off));
        float p = __expf(x - mx);
        float sden = p;
#pragma unroll
        for (int off = 32; off; off >>= 1) sden += __shfl_xor(sden, off);
        float score = p / sden;
        regSm += score;

        double vd = xd;
        int selIdx = 0; float selVal = 0.f;
#pragma unroll
        for (int r = 0; r < TK; ++r) {
            unsigned long long u = (unsigned long long)__double_as_longlong(vd);
            unsigned long long mk = (u & 0x8000000000000000ull) ? ~u : (u | 0x8000000000000000ull);
            unsigned long long key = (mk & 0xFFFFFFFFFFFFFFC0ull) | (unsigned long long)(63 - l);
#pragma unroll
            for (int off = 32; off; off >>= 1) {
                unsigned long long o = __shfl_xor(key, off);
                if (o > key) key = o;
            }
            int winner = 63 - (int)(key & 63ull);
            float wsc = __shfl(score, winner);
            if (l == r) { selIdx = winner; selVal = wsc; }
            if (l == winner) vd = -__builtin_inf();
        }
        float dv = (l < TK) ? selVal : 0.f;
#pragma unroll
        for (int off = 32; off; off >>= 1) dv += __shfl_xor(dv, off);
        int t = t0 + tt;
        if (l < TK) {
            out[(size_t)t * TK + l] = (float)selIdx;
            out[(size_t)NTOK * TK + (size_t)t * TK + l] = selVal / (dv + 1e-20f);
            atomicAdd(&hist[selIdx], 1);
        }
    }
    atomicAdd(&smSum[l], regSm);
    __syncthreads();
    if (tid < NEXP) {
        int b = blockIdx.x >> 6;            // 64 blocks per batch element
        atomicAdd(&ws[b * NEXP + tid], (float)hist[tid]);
        atomicAdd(&ws[NB * NEXP + b * NEXP + tid], smSum[tid]);
    }
}

__global__ void moe_finalize(const float* __restrict__ ws, float* __restrict__ out)
{
    int e = threadIdx.x;   // 64 threads
    float cnt = 0.f, accv = 0.f;
#pragma unroll
    for (int b = 0; b < NB; ++b) {
        float c  = ws[b * NEXP + e];
        float sm = ws[NB * NEXP + b * NEXP + e];
        cnt += c;
        accv += c * sm;
    }
    out[(size_t)NTOK * TK * 2 + 1 + e] = cnt;   // expert_counts (as float)
#pragma unroll
    for (int off = 32; off; off >>= 1) accv += __shfl_xor(accv, off);
    if (e == 0) {
        float aux = 0.01f * accv * ((float)NEXP / ((float)SEQ * (float)TK))
                    / (float)SEQ / (float)NB;
        out[(size_t)NTOK * TK * 2] = aux;
    }
}

extern "C" void kernel_launch(void* const* d_in, const int* in_sizes, int n_in,
                              void* d_out, int out_size, void* d_ws, size_t ws_size,
                              hipStream_t stream)
{
    const float* hidden = (const float*)d_in[0];
    const float* weight = (const float*)d_in[1];
    float* out  = (float*)d_out;
    float* wsf  = (float*)d_ws;
    unsigned short* whi = (unsigned short*)(wsf + 2 * NB * NEXP);   // +4096 B
    unsigned short* wlo = whi + NEXP * HDIM;

    hipMemsetAsync(d_ws, 0, 2 * NB * NEXP * sizeof(float), stream);
    wsplit<<<64, 256, 0, stream>>>(weight, whi, wlo);
    moe_main<<<NTOK / MB, NTHR, 0, stream>>>(hidden, whi, wlo, out, wsf);
    moe_finalize<<<1, 64, 0, stream>>>(wsf, out);
}

// Round 7
// 237.488 us; speedup vs baseline: 1.9900x; 1.1062x over previous
//
#include <hip/hip_runtime.h>

#define NTOK 32768      // 8*4096 tokens
#define HDIM 1024
#define NEXP 64
#define TK   8
#define NB   8
#define SEQ  4096

#define MB   64         // tokens per block
#define KC   64         // K chunk (16 chunks)
#define NCH  (HDIM / KC)
#define NTHR 128        // 2 waves; wave w owns token rows [32w, 32w+32)

typedef __attribute__((ext_vector_type(8))) short bf16x8;   // 8 bf16 = 4 VGPRs
typedef __attribute__((ext_vector_type(4))) float f32x4;

union BF8 { bf16x8 v; unsigned u[4]; };

__device__ inline unsigned f2bf(float x) {          // RTN-even fp32 -> bf16 bits
    unsigned u = __float_as_uint(x);
    return (u + 0x7FFFu + ((u >> 16) & 1u)) >> 16;
}

__device__ inline void split4(float4 v, unsigned* hp, unsigned* lp) {
    unsigned h0 = f2bf(v.x), h1 = f2bf(v.y), h2 = f2bf(v.z), h3 = f2bf(v.w);
    unsigned l0 = f2bf(v.x - __uint_as_float(h0 << 16));
    unsigned l1 = f2bf(v.y - __uint_as_float(h1 << 16));
    unsigned l2 = f2bf(v.z - __uint_as_float(h2 << 16));
    unsigned l3 = f2bf(v.w - __uint_as_float(h3 << 16));
    hp[0] = h0 | (h1 << 16); hp[1] = h2 | (h3 << 16);
    lp[0] = l0 | (l1 << 16); lp[1] = l2 | (l3 << 16);
}

// async global->LDS, 16B/lane; LDS dest = wave-uniform base + lane*16
__device__ __forceinline__ void gl16(const void* g, void* l) {
    __builtin_amdgcn_global_load_lds(
        (const __attribute__((address_space(1))) void*)g,
        (__attribute__((address_space(3))) void*)l, 16, 0, 0);
}

// One-time: split W into Dekker hi/lo bf16 AND pre-arrange in MFMA B-fragment
// order: slot(c,s,n) holds 64 lanes x 16B; lane l -> B[e=n*16+(l&15)]
// [k=c*64+s*32+(l>>4)*8 .. +8]. Main-loop B loads become coalesced 1KB dwordx4.
__global__ void wsplit(const float* __restrict__ w,
                       unsigned short* __restrict__ whi,
                       unsigned short* __restrict__ wlo)
{
    int T = blockIdx.x * 256 + threadIdx.x;     // 8192 threads = 128 slots x 64
    int slot = T >> 6, l = T & 63;
    int c = slot >> 3, s = (slot >> 2) & 1, n = slot & 3;
    int e = n * 16 + (l & 15);
    int k = c * 64 + s * 32 + (l >> 4) * 8;
    const float* src = w + (size_t)e * HDIM + k;
    float4 v0 = *(const float4*)(src);
    float4 v1 = *(const float4*)(src + 4);
    unsigned hp[4], lp[4];
    split4(v0, &hp[0], &lp[0]);
    split4(v1, &hp[2], &lp[2]);
    ((uint4*)whi)[T] = make_uint4(hp[0], hp[1], hp[2], hp[3]);
    ((uint4*)wlo)[T] = make_uint4(lp[0], lp[1], lp[2], lp[3]);
}

// Pipelined bf16x3 GEMM: single-barrier K-loop, double-buffered A via
// global_load_lds (XOR-swizzled for conflict-free ds_read_b128), B direct
// from fragment-ordered L2-resident workspace. Phase 2: shuffle softmax
// stats + per-lane serial top-8 (lane = token).
__global__ __launch_bounds__(NTHR, 2) void moe_main(
    const float* __restrict__ hidden,           // [NTOK][HDIM]
    const unsigned short* __restrict__ w2hi,    // frag-ordered bf16 hi
    const unsigned short* __restrict__ w2lo,    // frag-ordered bf16 lo
    float* __restrict__ out,                    // idx | w | aux | counts
    float* __restrict__ ws)                     // C[8][64] | Sm[8][64]
{
    __shared__ __align__(16) unsigned char smem[32768];     // A dbuf 2x16KB
    float* sLog = (float*)smem;                             // [64][66] alias
    __shared__ float mxArr[MB];
    __shared__ float smSum[NEXP];
    __shared__ int   hist[NEXP];

    const int tid   = threadIdx.x;
    const int w     = tid >> 6;
    const int l     = tid & 63;
    const int m     = l & 15;
    const int q     = l >> 4;
    const int t0    = blockIdx.x * MB;
    const int wbase = tid & 64;

    if (tid < NEXP) { smSum[tid] = 0.f; hist[tid] = 0; }

    f32x4 acc[2][4];
#pragma unroll
    for (int mt = 0; mt < 2; ++mt)
#pragma unroll
        for (int n = 0; n < 4; ++n) acc[mt][n] = (f32x4)0.f;

    // stage chunk 0 into buf 0 (XOR-swizzled source columns)
#pragma unroll
    for (int i = 0; i < 8; ++i) {
        int slot = i * NTHR + tid;
        int r = slot >> 4, p = slot & 15, b = p ^ (r & 15);
        gl16(hidden + (size_t)(t0 + r) * HDIM + b * 4,
             smem + (size_t)(i * NTHR + wbase) * 16);
    }
    __syncthreads();

    for (int c = 0; c < NCH; ++c) {
        const unsigned char* Ab = smem + (c & 1) * 16384;

        // B fragment loads FIRST (so vmcnt wait for B keeps A prefetch in flight)
        bf16x8 bh[2][4], bl[2][4];
#pragma unroll
        for (int s = 0; s < 2; ++s)
#pragma unroll
            for (int n = 0; n < 4; ++n) {
                size_t off = ((size_t)(c * 8 + s * 4 + n) * 64 + l) * 8;
                bh[s][n] = *(const bf16x8*)(w2hi + off);
                bl[s][n] = *(const bf16x8*)(w2lo + off);
            }

        // A prefetch for chunk c+1 into the other buffer
        if (c + 1 < NCH) {
            unsigned char* nb = smem + ((c + 1) & 1) * 16384;
            const int kc = (c + 1) * KC;
#pragma unroll
            for (int i = 0; i < 8; ++i) {
                int slot = i * NTHR + tid;
                int r = slot >> 4, p = slot & 15, b = p ^ (r & 15);
                gl16(hidden + (size_t)(t0 + r) * HDIM + kc + b * 4,
                     nb + (size_t)(i * NTHR + wbase) * 16);
            }
        }

        // compute chunk c: 2 K32-steps, wave tile M=32 (2 m-tiles) x N=64
#pragma unroll
        for (int s = 0; s < 2; ++s) {
            BF8 ah[2], al[2];
#pragma unroll
            for (int mt = 0; mt < 2; ++mt) {
                int r = w * 32 + mt * 16 + m;
                int b0 = s * 8 + q * 2;
                int p0 = b0 ^ (r & 15), p1 = (b0 + 1) ^ (r & 15);
                float4 a0 = *(const float4*)(Ab + ((size_t)r * 16 + p0) * 16);
                float4 a1 = *(const float4*)(Ab + ((size_t)r * 16 + p1) * 16);
                split4(a0, &ah[mt].u[0], &al[mt].u[0]);
                split4(a1, &ah[mt].u[2], &al[mt].u[2]);
            }
#pragma unroll
            for (int n = 0; n < 4; ++n)
#pragma unroll
                for (int mt = 0; mt < 2; ++mt) {
                    acc[mt][n] = __builtin_amdgcn_mfma_f32_16x16x32_bf16(ah[mt].v, bh[s][n], acc[mt][n], 0, 0, 0);
                    acc[mt][n] = __builtin_amdgcn_mfma_f32_16x16x32_bf16(al[mt].v, bh[s][n], acc[mt][n], 0, 0, 0);
                    acc[mt][n] = __builtin_amdgcn_mfma_f32_16x16x32_bf16(ah[mt].v, bl[s][n], acc[mt][n], 0, 0, 0);
                }
        }
        __syncthreads();    // one barrier/chunk: A(c+1) drain overlapped compute
    }

    // epilogue: C/D layout row=(lane>>4)*4+reg (token), col=lane&15 (expert)
#pragma unroll
    for (int mt = 0; mt < 2; ++mt)
#pragma unroll
        for (int n = 0; n < 4; ++n)
#pragma unroll
            for (int r = 0; r < 4; ++r)
                sLog[(w * 32 + mt * 16 + q * 4 + r) * 66 + n * 16 + m] = acc[mt][n][r];
    __syncthreads();

    // ---- phase 2a: softmax stats (lane = expert); wave w: tokens [32w,32w+32)
    float regSm = 0.f;
    for (int j = 0; j < 32; ++j) {
        int t = w * 32 + j;
        float x = sLog[t * 66 + l];
        float mx = x;
#pragma unroll
        for (int off = 32; off; off >>= 1) mx = fmaxf(mx, __shfl_xor(mx, off));
        float p = __expf(x - mx);
        float sd = p;
#pragma unroll
        for (int off = 32; off; off >>= 1) sd += __shfl_xor(sd, off);
        regSm += p / sd;
        if (l == 0) mxArr[t] = mx;
    }
    atomicAdd(&smSum[l], regSm);
    __syncthreads();

    // ---- phase 2b: top-8 per token, lane = token (wave 0 only) ----
    if (w == 0) {
        const float mx = mxArr[l];
        unsigned long long s8[TK];
#pragma unroll
        for (int j = 0; j < TK; ++j) s8[j] = 0ull;
        for (int e = 0; e < NEXP; ++e) {
            float x = sLog[l * 66 + e];
            unsigned u = __float_as_uint(x);
            unsigned k32 = (u & 0x80000000u) ? ~u : (u | 0x80000000u);
            unsigned long long key = ((unsigned long long)k32 << 6)
                                   | (unsigned long long)(63 - e);
            if (key > s8[TK - 1]) {
#pragma unroll
                for (int j = 0; j < TK; ++j) {
                    unsigned long long hi = s8[j] > key ? s8[j] : key;
                    key = s8[j] > key ? key : s8[j];
                    s8[j] = hi;
                }
            }
        }
        float ev[TK]; int ei[TK]; float sum = 0.f;
#pragma unroll
        for (int j = 0; j < TK; ++j) {
            unsigned k32 = (unsigned)(s8[j] >> 6);
            unsigned u = (k32 >> 31) ? (k32 ^ 0x80000000u) : ~k32;
            ev[j] = __expf(__uint_as_float(u) - mx);
            sum += ev[j];
            ei[j] = 63 - (int)(s8[j] & 63ull);
        }
        int t = t0 + l;
        float4 i0 = make_float4((float)ei[0], (float)ei[1], (float)ei[2], (float)ei[3]);
        float4 i1 = make_float4((float)ei[4], (float)ei[5], (float)ei[6], (float)ei[7]);
        *(float4*)(out + (size_t)t * TK)     = i0;
        *(float4*)(out + (size_t)t * TK + 4) = i1;
        float rs = 1.f / (sum + 1e-20f);
        float4 w0 = make_float4(ev[0] * rs, ev[1] * rs, ev[2] * rs, ev[3] * rs);
        float4 w1 = make_float4(ev[4] * rs, ev[5] * rs, ev[6] * rs, ev[7] * rs);
        *(float4*)(out + (size_t)NTOK * TK + (size_t)t * TK)     = w0;
        *(float4*)(out + (size_t)NTOK * TK + (size_t)t * TK + 4) = w1;
#pragma unroll
        for (int j = 0; j < TK; ++j) atomicAdd(&hist[ei[j]], 1);
    }
    __syncthreads();

    if (tid < NEXP) {
        int b = blockIdx.x >> 6;            // 64 blocks per batch element
        atomicAdd(&ws[b * NEXP + tid], (float)hist[tid]);
        atomicAdd(&ws[NB * NEXP + b * NEXP + tid], smSum[tid]);
    }
}

__global__ void moe_finalize(const float* __restrict__ ws, float* __restrict__ out)
{
    int e = threadIdx.x;   // 64 threads
    float cnt = 0.f, accv = 0.f;
#pragma unroll
    for (int b = 0; b < NB; ++b) {
        float c  = ws[b * NEXP + e];
        float sm = ws[NB * NEXP + b * NEXP + e];
        cnt += c;
        accv += c * sm;
    }
    out[(size_t)NTOK * TK * 2 + 1 + e] = cnt;   // expert_counts (as float)
#pragma unroll
    for (int off = 32; off; off >>= 1) accv += __shfl_xor(accv, off);
    if (e == 0) {
        float aux = 0.01f * accv * ((float)NEXP / ((float)SEQ * (float)TK))
                    / (float)SEQ / (float)NB;
        out[(size_t)NTOK * TK * 2] = aux;
    }
}

extern "C" void kernel_launch(void* const* d_in, const int* in_sizes, int n_in,
                              void* d_out, int out_size, void* d_ws, size_t ws_size,
                              hipStream_t stream)
{
    const float* hidden = (const float*)d_in[0];
    const float* weight = (const float*)d_in[1];
    float* out  = (float*)d_out;
    float* wsf  = (float*)d_ws;
    unsigned short* w2hi = (unsigned short*)(wsf + 2 * NB * NEXP);  // +4096 B
    unsigned short* w2lo = w2hi + NEXP * HDIM;

    hipMemsetAsync(d_ws, 0, 2 * NB * NEXP * sizeof(float), stream);
    wsplit<<<32, 256, 0, stream>>>(weight, w2hi, w2lo);
    moe_main<<<NTOK / MB, NTHR, 0, stream>>>(hidden, w2hi, w2lo, out, wsf);
    moe_finalize<<<1, 64, 0, stream>>>(wsf, out);
}